// Round 8
// baseline (172673.767 us; speedup 1.0000x reference)
//
#include <hip/hip_runtime.h>
#include <hip/hip_bf16.h>

#define BB 2
#define SS 2048
#define NH 32
#define NKV 8
#define GQ (NH / NKV)
#define DD 128
#define QBLK 128
#define KVBLK 64
#define NQT (SS / QBLK)
#define NTHREADS 512

typedef __bf16 bf16x8 __attribute__((ext_vector_type(8)));
typedef short short8 __attribute__((ext_vector_type(8)));
typedef unsigned int u32x4 __attribute__((ext_vector_type(4)));

__device__ inline bf16x8 cvt_bf16x8(float4 a, float4 b) {
  bf16x8 r;
  r[0] = (__bf16)a.x; r[1] = (__bf16)a.y; r[2] = (__bf16)a.z; r[3] = (__bf16)a.w;
  r[4] = (__bf16)b.x; r[5] = (__bf16)b.y; r[6] = (__bf16)b.z; r[7] = (__bf16)b.w;
  return r;
}

__device__ inline float bf2f(short s) {
  unsigned u = ((unsigned)(unsigned short)s) << 16;
  return __builtin_bit_cast(float, u);
}

// COMPUTE-DIFFERENTIAL PROBE (resubmit of R7; prior run died on infra).
// Same as R6 (plain + swizzled buffers, byte-compare flags) PLUS duplicate
// arithmetic fed from the SWIZZLED registers, compared against plain-fed.
// Flags: K byte:+1e2, V byte:+1e4, P byte:+1e6, S-diverge:+1e8, O-diverge:+1e10
__global__ __launch_bounds__(NTHREADS, 1)
void attn_diff2(const float* __restrict__ qp, const float* __restrict__ kp,
                const float* __restrict__ vp, float* __restrict__ op)
{
  __shared__ u32x4 qbuf[8 * 16 * 16];
  __shared__ short kplain[KVBLK][DD];
  __shared__ short vplain[DD][KVBLK];
  __shared__ short pplain[8][16][KVBLK];
  __shared__ u32x4 kswz[KVBLK * 16];
  __shared__ u32x4 vswz[DD * 8];
  __shared__ u32x4 pswz[8 * 16 * 8];

  const int tid  = threadIdx.x;
  const int wave = tid >> 6;
  const int lane = tid & 63;
  const int lhi  = lane >> 4;
  const int llo  = lane & 15;

  const int bid = blockIdx.x;
  const int bh  = bid % (BB * NH);
  const int qt  = NQT - 1 - bid / (BB * NH);
  const int b   = bh / NH;
  const int h   = bh % NH;
  const int kh  = h / GQ;

  const int q0 = qt * QBLK;
  const int qw = q0 + wave * 16;

  const float scale = 0.08838834764831845f;   // 1/sqrt(128)

  u32x4* qbuf_w = qbuf + wave * 256;
  {
    const float* qrow = qp + (((size_t)b * SS + (qw + llo)) * NH + h) * DD;
    #pragma unroll
    for (int kc = 0; kc < 4; ++kc) {
      const int d0 = kc * 32 + lhi * 8;
      float4 a = *(const float4*)(qrow + d0);
      float4 c = *(const float4*)(qrow + d0 + 4);
      a.x *= scale; a.y *= scale; a.z *= scale; a.w *= scale;
      c.x *= scale; c.y *= scale; c.z *= scale; c.w *= scale;
      qbuf_w[llo * 16 + kc * 4 + lhi] = __builtin_bit_cast(u32x4, cvt_bf16x8(a, c));
    }
  }

  float oaccf[8][4];
  #pragma unroll
  for (int f = 0; f < 8; ++f)
    #pragma unroll
    for (int j = 0; j < 4; ++j) oaccf[f][j] = 0.f;
  float m_i[4], l_i[4];
  #pragma unroll
  for (int j = 0; j < 4; ++j) { m_i[j] = -1e30f; l_i[j] = 0.f; }

  int kflag = 0, vflag = 0, pflag = 0, sflag = 0, oflag = 0;

  const int ntiles = q0 / KVBLK + 2;

  short* vswz_s = (short*)vswz;
  short* pswz_s = (short*)(pswz + wave * 128);
  const u32x4* pswz_w = pswz + wave * 128;

  for (int t = 0; t < ntiles; ++t) {
    const int t0 = t * KVBLK;
    __syncthreads();

    #pragma unroll
    for (int it = 0; it < 2; ++it) {
      const int c   = tid + it * NTHREADS;
      const int row = c >> 4, c16 = c & 15;
      const float* src = kp + (((size_t)b * SS + (t0 + row)) * NKV + kh) * DD + c16 * 8;
      float4 a = *(const float4*)src;
      float4 d = *(const float4*)(src + 4);
      bf16x8 e = cvt_bf16x8(a, d);
      kswz[row * 16 + (c16 ^ (row & 7))] = __builtin_bit_cast(u32x4, e);
      short8 es = __builtin_bit_cast(short8, e);
      #pragma unroll
      for (int j = 0; j < 8; ++j) kplain[row][c16 * 8 + j] = es[j];
    }
    #pragma unroll
    for (int it = 0; it < 2; ++it) {
      const int c  = tid + it * NTHREADS;
      const int dg = c >> 6, tt = c & 63;
      const float* src = vp + (((size_t)b * SS + (t0 + tt)) * NKV + kh) * DD + dg * 8;
      float4 a  = *(const float4*)src;
      float4 d4 = *(const float4*)(src + 4);
      bf16x8 e = cvt_bf16x8(a, d4);
      short8 es = __builtin_bit_cast(short8, e);
      #pragma unroll
      for (int j = 0; j < 8; ++j) {
        const int dd = dg * 8 + j;
        vplain[dd][tt] = es[j];
        vswz_s[(dd * 8 + ((tt >> 3) ^ (dd & 7))) * 8 + (tt & 7)] = es[j];
      }
    }
    __syncthreads();

    if (t0 > qw + 15) continue;

    // ---- QK^T: plain-fed acc AND swizzle-fed accS ----
    float sf[4][4];
    #pragma unroll
    for (int cc = 0; cc < 4; ++cc) {
      const int r = cc * 16 + llo;
      #pragma unroll
      for (int j = 0; j < 4; ++j) {
        const int row = lhi * 4 + j;
        float acc = 0.f, accS = 0.f;
        #pragma unroll
        for (int s8 = 0; s8 < 16; ++s8) {
          short8 qv = __builtin_bit_cast(short8, qbuf_w[row * 16 + s8]);
          short8 ks = __builtin_bit_cast(short8, kswz[r * 16 + (s8 ^ (r & 7))]);
          #pragma unroll
          for (int e = 0; e < 8; ++e) {
            const short kpv = kplain[r][s8 * 8 + e];
            kflag |= (kpv != ks[e]);
            acc  += bf2f(qv[e]) * bf2f(kpv);
            accS += bf2f(qv[e]) * bf2f(ks[e]);
          }
        }
        sflag |= (__builtin_fabsf(acc - accS) > 1e-4f);
        sf[cc][j] = acc;
      }
    }

    if (t0 + KVBLK - 1 > qw) {
      #pragma unroll
      for (int cc = 0; cc < 4; ++cc)
        #pragma unroll
        for (int j = 0; j < 4; ++j) {
          const int tg = t0 + cc * 16 + llo;
          const int qg = qw + lhi * 4 + j;
          if (tg > qg) sf[cc][j] = -1e30f;
        }
    }

    #pragma unroll
    for (int j = 0; j < 4; ++j) {
      float mx = fmaxf(fmaxf(sf[0][j], sf[1][j]), fmaxf(sf[2][j], sf[3][j]));
      #pragma unroll
      for (int off = 1; off < 16; off <<= 1)
        mx = fmaxf(mx, __shfl_xor(mx, off));
      const float mnew = fmaxf(m_i[j], mx);
      const float corr = __expf(m_i[j] - mnew);
      m_i[j] = mnew;
      float s = 0.f;
      #pragma unroll
      for (int cc = 0; cc < 4; ++cc) {
        const float p = __expf(sf[cc][j] - mnew);
        sf[cc][j] = p;
        s += p;
      }
      #pragma unroll
      for (int off = 1; off < 16; off <<= 1)
        s += __shfl_xor(s, off);
      l_i[j] = l_i[j] * corr + s;
      #pragma unroll
      for (int f = 0; f < 8; ++f) oaccf[f][j] *= corr;
    }

    #pragma unroll
    for (int cc = 0; cc < 4; ++cc) {
      #pragma unroll
      for (int j = 0; j < 4; ++j) {
        const int row = lhi * 4 + j;
        const int col = cc * 16 + llo;
        const short pb = __builtin_bit_cast(short, (__bf16)sf[cc][j]);
        pplain[wave][row][col] = pb;
        pswz_s[(row * 8 + ((col >> 3) ^ (row & 7))) * 8 + (col & 7)] = pb;
      }
    }

    asm volatile("s_waitcnt lgkmcnt(0)" ::: "memory");
    __builtin_amdgcn_sched_barrier(0);

    // ---- PV: plain-fed acc AND swizzle-fed accS ----
    #pragma unroll
    for (int f = 0; f < 8; ++f) {
      const int dd = f * 16 + llo;
      #pragma unroll
      for (int j = 0; j < 4; ++j) {
        const int row = lhi * 4 + j;
        float acc = 0.f, accS = 0.f;
        #pragma unroll
        for (int s8 = 0; s8 < 8; ++s8) {
          short8 pv = __builtin_bit_cast(short8, pswz_w[row * 8 + (s8 ^ (row & 7))]);
          short8 vv = __builtin_bit_cast(short8, vswz[dd * 8 + (s8 ^ (dd & 7))]);
          #pragma unroll
          for (int e = 0; e < 8; ++e) {
            const short ppv = pplain[wave][row][s8 * 8 + e];
            const short vvv = vplain[dd][s8 * 8 + e];
            pflag |= (ppv != pv[e]);
            vflag |= (vvv != vv[e]);
            acc  += bf2f(ppv) * bf2f(vvv);
            accS += bf2f(pv[e]) * bf2f(vv[e]);
          }
        }
        oflag |= (__builtin_fabsf(acc - accS) > 1e-4f);
        oaccf[f][j] += acc;
      }
    }
  }

  const float flagadd = kflag * 1e2f + vflag * 1e4f + pflag * 1e6f
                      + sflag * 1e8f + oflag * 1e10f;
  #pragma unroll
  for (int j = 0; j < 4; ++j) {
    const float inv = 1.f / l_i[j];
    const int qg = qw + lhi * 4 + j;
    float* orow = op + (((size_t)b * SS + qg) * NH + h) * DD;
    #pragma unroll
    for (int f = 0; f < 8; ++f)
      orow[f * 16 + llo] = oaccf[f][j] * inv + flagadd;
  }
}

extern "C" void kernel_launch(void* const* d_in, const int* in_sizes, int n_in,
                              void* d_out, int out_size, void* d_ws, size_t ws_size,
                              hipStream_t stream) {
  const float* q = (const float*)d_in[0];
  const float* k = (const float*)d_in[1];
  const float* v = (const float*)d_in[2];
  float* out = (float*)d_out;
  dim3 grid(BB * NH * NQT);
  dim3 block(NTHREADS);
  attn_diff2<<<grid, block, 0, stream>>>(q, k, v, out);
}

// Round 9
// 311.813 us; speedup vs baseline: 553.7733x; 553.7733x over previous
//
#include <hip/hip_runtime.h>
#include <hip/hip_bf16.h>

#define BB 2
#define SS 2048
#define NH 32
#define NKV 8
#define GQ (NH / NKV)
#define DD 128
#define QBLK 128
#define KVBLK 64
#define NQT (SS / QBLK)
#define NTHREADS 512

typedef __bf16 bf16x8 __attribute__((ext_vector_type(8)));
typedef short short8 __attribute__((ext_vector_type(8)));
typedef float f32x4 __attribute__((ext_vector_type(4)));
typedef unsigned int u32x4 __attribute__((ext_vector_type(4)));

__device__ inline bf16x8 cvt_bf16x8(float4 a, float4 b) {
  bf16x8 r;
  r[0] = (__bf16)a.x; r[1] = (__bf16)a.y; r[2] = (__bf16)a.z; r[3] = (__bf16)a.w;
  r[4] = (__bf16)b.x; r[5] = (__bf16)b.y; r[6] = (__bf16)b.z; r[7] = (__bf16)b.w;
  return r;
}

// MFMA on PLAIN (unswizzled) bf16 LDS. Data layer byte-certified by R5/R6/R8;
// this isolates the MFMA fragment consumption as the only untested layer.
// Bank conflicts accepted this round; swizzle returns incrementally later.
__global__ __launch_bounds__(NTHREADS, 2)
void attn_mfma_plain(const float* __restrict__ qp, const float* __restrict__ kp,
                     const float* __restrict__ vp, float* __restrict__ op)
{
  __shared__ __align__(16) short kpl[KVBLK][DD];     // K tile bf16, 16KB
  __shared__ __align__(16) short vtp[DD][KVBLK];     // V^T tile bf16, 16KB
  __shared__ __align__(16) short ppl[8][16][KVBLK];  // per-wave P bf16, 16KB

  const int tid  = threadIdx.x;
  const int wave = tid >> 6;
  const int lane = tid & 63;
  const int lhi  = lane >> 4;
  const int llo  = lane & 15;

  const int bid = blockIdx.x;
  const int bh  = bid % (BB * NH);
  const int qt  = NQT - 1 - bid / (BB * NH);   // heavy q-tiles first
  const int b   = bh / NH;
  const int h   = bh % NH;
  const int kh  = h / GQ;

  const int q0 = qt * QBLK;
  const int qw = q0 + wave * 16;

  const float scale = 0.08838834764831845f;    // 1/sqrt(128)

  // ---- Q fragments in registers (values byte-certified via R5's qbuf) ----
  bf16x8 qf[4];
  {
    const float* qrow = qp + (((size_t)b * SS + (qw + llo)) * NH + h) * DD;
    #pragma unroll
    for (int kc = 0; kc < 4; ++kc) {
      const int d0 = kc * 32 + lhi * 8;
      float4 a = *(const float4*)(qrow + d0);
      float4 c = *(const float4*)(qrow + d0 + 4);
      a.x *= scale; a.y *= scale; a.z *= scale; a.w *= scale;
      c.x *= scale; c.y *= scale; c.z *= scale; c.w *= scale;
      qf[kc] = cvt_bf16x8(a, c);
    }
  }

  f32x4 oacc[8];
  #pragma unroll
  for (int f = 0; f < 8; ++f) oacc[f] = (f32x4){0.f, 0.f, 0.f, 0.f};
  float m_i[4], l_i[4];
  #pragma unroll
  for (int j = 0; j < 4; ++j) { m_i[j] = -1e30f; l_i[j] = 0.f; }

  const int ntiles = q0 / KVBLK + 2;

  for (int t = 0; t < ntiles; ++t) {
    const int t0 = t * KVBLK;
    __syncthreads();

    // ---- stage K tile (bf16, plain): one 16B store per (row, c16) ----
    #pragma unroll
    for (int it = 0; it < 2; ++it) {
      const int c   = tid + it * NTHREADS;     // 0..1023
      const int row = c >> 4, c16 = c & 15;
      const float* src = kp + (((size_t)b * SS + (t0 + row)) * NKV + kh) * DD + c16 * 8;
      float4 a = *(const float4*)src;
      float4 d = *(const float4*)(src + 4);
      *(u32x4*)&kpl[row][c16 * 8] = __builtin_bit_cast(u32x4, cvt_bf16x8(a, d));
    }
    // ---- stage V^T tile (bf16, plain scalar scatter; R5-verified pattern) ----
    #pragma unroll
    for (int it = 0; it < 2; ++it) {
      const int c  = tid + it * NTHREADS;
      const int dg = c >> 6, tt = c & 63;
      const float* src = vp + (((size_t)b * SS + (t0 + tt)) * NKV + kh) * DD + dg * 8;
      float4 a  = *(const float4*)src;
      float4 d4 = *(const float4*)(src + 4);
      short8 es = __builtin_bit_cast(short8, cvt_bf16x8(a, d4));
      #pragma unroll
      for (int j = 0; j < 8; ++j) vtp[dg * 8 + j][tt] = es[j];
    }
    __syncthreads();

    if (t0 > qw + 15) continue;   // wave-uniform skip (barrier count unchanged)

    // ---- QK^T: S[16 q][64 t], 4 col-chunk MFMAs ----
    f32x4 sfrag[4];
    #pragma unroll
    for (int cc = 0; cc < 4; ++cc) {
      f32x4 acc = (f32x4){0.f, 0.f, 0.f, 0.f};
      const int r = cc * 16 + llo;             // K row for B-fragment
      #pragma unroll
      for (int kc = 0; kc < 4; ++kc) {
        u32x4 kb = *(const u32x4*)&kpl[r][(kc * 4 + lhi) * 8];
        acc = __builtin_amdgcn_mfma_f32_16x16x32_bf16(
                  qf[kc], __builtin_bit_cast(bf16x8, kb), acc, 0, 0, 0);
      }
      sfrag[cc] = acc;
    }

    // ---- causal mask (C/D layout: col=llo, row=lhi*4+j; m89-verified) ----
    if (t0 + KVBLK - 1 > qw) {
      #pragma unroll
      for (int cc = 0; cc < 4; ++cc)
        #pragma unroll
        for (int j = 0; j < 4; ++j) {
          const int tg = t0 + cc * 16 + llo;
          const int qg = qw + lhi * 4 + j;
          if (tg > qg) sfrag[cc][j] = -1e30f;
        }
    }

    // ---- online softmax (16-lane column groups) ----
    #pragma unroll
    for (int j = 0; j < 4; ++j) {
      float mx = fmaxf(fmaxf(sfrag[0][j], sfrag[1][j]), fmaxf(sfrag[2][j], sfrag[3][j]));
      #pragma unroll
      for (int off = 1; off < 16; off <<= 1)
        mx = fmaxf(mx, __shfl_xor(mx, off));
      const float mnew = fmaxf(m_i[j], mx);
      const float corr = __expf(m_i[j] - mnew);
      m_i[j] = mnew;
      float s = 0.f;
      #pragma unroll
      for (int cc = 0; cc < 4; ++cc) {
        const float p = __expf(sfrag[cc][j] - mnew);
        sfrag[cc][j] = p;
        s += p;
      }
      #pragma unroll
      for (int off = 1; off < 16; off <<= 1)
        s += __shfl_xor(s, off);
      l_i[j] = l_i[j] * corr + s;
      #pragma unroll
      for (int f = 0; f < 8; ++f) oacc[f][j] *= corr;
    }

    // ---- P -> per-wave plain LDS (scalar bf16 stores; R6-certified pair) ----
    #pragma unroll
    for (int cc = 0; cc < 4; ++cc)
      #pragma unroll
      for (int j = 0; j < 4; ++j)
        ppl[wave][lhi * 4 + j][cc * 16 + llo] =
            __builtin_bit_cast(short, (__bf16)sfrag[cc][j]);

    asm volatile("s_waitcnt lgkmcnt(0)" ::: "memory");
    __builtin_amdgcn_sched_barrier(0);

    // ---- PV: O[16 q][128 d] += P[16][64] * V[64][128] ----
    #pragma unroll
    for (int kc2 = 0; kc2 < 2; ++kc2) {
      u32x4 pa = *(const u32x4*)&ppl[wave][llo][(kc2 * 4 + lhi) * 8];
      #pragma unroll
      for (int f = 0; f < 8; ++f) {
        u32x4 vb = *(const u32x4*)&vtp[f * 16 + llo][(kc2 * 4 + lhi) * 8];
        oacc[f] = __builtin_amdgcn_mfma_f32_16x16x32_bf16(
                      __builtin_bit_cast(bf16x8, pa),
                      __builtin_bit_cast(bf16x8, vb), oacc[f], 0, 0, 0);
      }
    }
  }

  // ---- epilogue: O / l (R5-verified) ----
  #pragma unroll
  for (int j = 0; j < 4; ++j) {
    const float inv = 1.f / l_i[j];
    const int qg = qw + lhi * 4 + j;
    float* orow = op + (((size_t)b * SS + qg) * NH + h) * DD;
    #pragma unroll
    for (int f = 0; f < 8; ++f)
      orow[f * 16 + llo] = oacc[f][j] * inv;
  }
}

extern "C" void kernel_launch(void* const* d_in, const int* in_sizes, int n_in,
                              void* d_out, int out_size, void* d_ws, size_t ws_size,
                              hipStream_t stream) {
  const float* q = (const float*)d_in[0];
  const float* k = (const float*)d_in[1];
  const float* v = (const float*)d_in[2];
  float* out = (float*)d_out;
  dim3 grid(BB * NH * NQT);
  dim3 block(NTHREADS);
  attn_mfma_plain<<<grid, block, 0, stream>>>(q, k, v, out);
}

// Round 10
// 185.588 us; speedup vs baseline: 930.4151x; 1.6801x over previous
//
#include <hip/hip_runtime.h>
#include <hip/hip_bf16.h>

#define BB 2
#define SS 2048
#define NH 32
#define NKV 8
#define GQ (NH / NKV)
#define DD 128
#define QBLK 128
#define KVBLK 64
#define NQT (SS / QBLK)
#define NTHREADS 512

// +8 shorts (16B) padding on LDS leading dims: breaks the 16-way bank
// conflict on MFMA fragment reads (row stride 272B/144B -> start bank
// varies with row -> 2-way aliasing = free per m136). No XOR swizzle.
#define KPAD (DD + 8)
#define VPAD (KVBLK + 8)

typedef __bf16 bf16x8 __attribute__((ext_vector_type(8)));
typedef short short8 __attribute__((ext_vector_type(8)));
typedef float f32x4 __attribute__((ext_vector_type(4)));
typedef unsigned int u32x4 __attribute__((ext_vector_type(4)));

__device__ inline bf16x8 cvt_bf16x8(float4 a, float4 b) {
  bf16x8 r;
  r[0] = (__bf16)a.x; r[1] = (__bf16)a.y; r[2] = (__bf16)a.z; r[3] = (__bf16)a.w;
  r[4] = (__bf16)b.x; r[5] = (__bf16)b.y; r[6] = (__bf16)b.z; r[7] = (__bf16)b.w;
  return r;
}

__global__ __launch_bounds__(NTHREADS, 2)
void attn_mfma_pad(const float* __restrict__ qp, const float* __restrict__ kp,
                   const float* __restrict__ vp, float* __restrict__ op)
{
  __shared__ __align__(16) short kpl[KVBLK][KPAD];     // 17.4KB
  __shared__ __align__(16) short vtp[DD][VPAD];        // 18.4KB
  __shared__ __align__(16) short ppl[8][16][VPAD];     // 18.4KB

  const int tid  = threadIdx.x;
  const int wave = tid >> 6;
  const int lane = tid & 63;
  const int lhi  = lane >> 4;
  const int llo  = lane & 15;

  const int bid = blockIdx.x;
  const int bh  = bid % (BB * NH);
  const int qt  = NQT - 1 - bid / (BB * NH);   // heavy q-tiles first
  const int b   = bh / NH;
  const int h   = bh % NH;
  const int kh  = h / GQ;

  const int q0 = qt * QBLK;
  const int qw = q0 + wave * 16;

  const float scale = 0.08838834764831845f;    // 1/sqrt(128)

  // ---- Q fragments in registers ----
  bf16x8 qf[4];
  {
    const float* qrow = qp + (((size_t)b * SS + (qw + llo)) * NH + h) * DD;
    #pragma unroll
    for (int kc = 0; kc < 4; ++kc) {
      const int d0 = kc * 32 + lhi * 8;
      float4 a = *(const float4*)(qrow + d0);
      float4 c = *(const float4*)(qrow + d0 + 4);
      a.x *= scale; a.y *= scale; a.z *= scale; a.w *= scale;
      c.x *= scale; c.y *= scale; c.z *= scale; c.w *= scale;
      qf[kc] = cvt_bf16x8(a, c);
    }
  }

  f32x4 oacc[8];
  #pragma unroll
  for (int f = 0; f < 8; ++f) oacc[f] = (f32x4){0.f, 0.f, 0.f, 0.f};
  float m_i[4], l_i[4];
  #pragma unroll
  for (int j = 0; j < 4; ++j) { m_i[j] = -1e30f; l_i[j] = 0.f; }

  const int ntiles = q0 / KVBLK + 2;

  for (int t = 0; t < ntiles; ++t) {
    const int t0 = t * KVBLK;
    __syncthreads();

    // ---- stage K tile (bf16): one 16B store per (row, c16) ----
    #pragma unroll
    for (int it = 0; it < 2; ++it) {
      const int c   = tid + it * NTHREADS;     // 0..1023
      const int row = c >> 4, c16 = c & 15;
      const float* src = kp + (((size_t)b * SS + (t0 + row)) * NKV + kh) * DD + c16 * 8;
      float4 a = *(const float4*)src;
      float4 d = *(const float4*)(src + 4);
      *(u32x4*)&kpl[row][c16 * 8] = __builtin_bit_cast(u32x4, cvt_bf16x8(a, d));
    }
    // ---- stage V^T tile (bf16, scalar scatter) ----
    #pragma unroll
    for (int it = 0; it < 2; ++it) {
      const int c  = tid + it * NTHREADS;
      const int dg = c >> 6, tt = c & 63;
      const float* src = vp + (((size_t)b * SS + (t0 + tt)) * NKV + kh) * DD + dg * 8;
      float4 a  = *(const float4*)src;
      float4 d4 = *(const float4*)(src + 4);
      short8 es = __builtin_bit_cast(short8, cvt_bf16x8(a, d4));
      #pragma unroll
      for (int j = 0; j < 8; ++j) vtp[dg * 8 + j][tt] = es[j];
    }
    __syncthreads();

    if (t0 > qw + 15) continue;   // wave-uniform skip (barrier count unchanged)

    // ---- QK^T: S[16 q][64 t], 4 col-chunk MFMAs ----
    f32x4 sfrag[4];
    #pragma unroll
    for (int cc = 0; cc < 4; ++cc) {
      f32x4 acc = (f32x4){0.f, 0.f, 0.f, 0.f};
      const int r = cc * 16 + llo;             // K row for B-fragment
      #pragma unroll
      for (int kc = 0; kc < 4; ++kc) {
        u32x4 kb = *(const u32x4*)&kpl[r][(kc * 4 + lhi) * 8];
        acc = __builtin_amdgcn_mfma_f32_16x16x32_bf16(
                  qf[kc], __builtin_bit_cast(bf16x8, kb), acc, 0, 0, 0);
      }
      sfrag[cc] = acc;
    }

    // ---- causal mask ----
    if (t0 + KVBLK - 1 > qw) {
      #pragma unroll
      for (int cc = 0; cc < 4; ++cc)
        #pragma unroll
        for (int j = 0; j < 4; ++j) {
          const int tg = t0 + cc * 16 + llo;
          const int qg = qw + lhi * 4 + j;
          if (tg > qg) sfrag[cc][j] = -1e30f;
        }
    }

    // ---- online softmax (16-lane column groups) ----
    #pragma unroll
    for (int j = 0; j < 4; ++j) {
      float mx = fmaxf(fmaxf(sfrag[0][j], sfrag[1][j]), fmaxf(sfrag[2][j], sfrag[3][j]));
      #pragma unroll
      for (int off = 1; off < 16; off <<= 1)
        mx = fmaxf(mx, __shfl_xor(mx, off));
      const float mnew = fmaxf(m_i[j], mx);
      const float corr = __expf(m_i[j] - mnew);
      m_i[j] = mnew;
      float s = 0.f;
      #pragma unroll
      for (int cc = 0; cc < 4; ++cc) {
        const float p = __expf(sfrag[cc][j] - mnew);
        sfrag[cc][j] = p;
        s += p;
      }
      #pragma unroll
      for (int off = 1; off < 16; off <<= 1)
        s += __shfl_xor(s, off);
      l_i[j] = l_i[j] * corr + s;
      #pragma unroll
      for (int f = 0; f < 8; ++f) oacc[f][j] *= corr;
    }

    // ---- P -> per-wave LDS (scalar bf16 stores) ----
    #pragma unroll
    for (int cc = 0; cc < 4; ++cc)
      #pragma unroll
      for (int j = 0; j < 4; ++j)
        ppl[wave][lhi * 4 + j][cc * 16 + llo] =
            __builtin_bit_cast(short, (__bf16)sfrag[cc][j]);

    asm volatile("s_waitcnt lgkmcnt(0)" ::: "memory");
    __builtin_amdgcn_sched_barrier(0);

    // ---- PV: O[16 q][128 d] += P[16][64] * V[64][128] ----
    #pragma unroll
    for (int kc2 = 0; kc2 < 2; ++kc2) {
      u32x4 pa = *(const u32x4*)&ppl[wave][llo][(kc2 * 4 + lhi) * 8];
      #pragma unroll
      for (int f = 0; f < 8; ++f) {
        u32x4 vb = *(const u32x4*)&vtp[f * 16 + llo][(kc2 * 4 + lhi) * 8];
        oacc[f] = __builtin_amdgcn_mfma_f32_16x16x32_bf16(
                      __builtin_bit_cast(bf16x8, pa),
                      __builtin_bit_cast(bf16x8, vb), oacc[f], 0, 0, 0);
      }
    }
  }

  // ---- epilogue: O / l ----
  #pragma unroll
  for (int j = 0; j < 4; ++j) {
    const float inv = 1.f / l_i[j];
    const int qg = qw + lhi * 4 + j;
    float* orow = op + (((size_t)b * SS + qg) * NH + h) * DD;
    #pragma unroll
    for (int f = 0; f < 8; ++f)
      orow[f * 16 + llo] = oacc[f][j] * inv;
  }
}

extern "C" void kernel_launch(void* const* d_in, const int* in_sizes, int n_in,
                              void* d_out, int out_size, void* d_ws, size_t ws_size,
                              hipStream_t stream) {
  const float* q = (const float*)d_in[0];
  const float* k = (const float*)d_in[1];
  const float* v = (const float*)d_in[2];
  float* out = (float*)d_out;
  dim3 grid(BB * NH * NQT);
  dim3 block(NTHREADS);
  attn_mfma_pad<<<grid, block, 0, stream>>>(q, k, v, out);
}